// Round 8
// baseline (1314.273 us; speedup 1.0000x reference)
//
#include <hip/hip_runtime.h>
#include <hip/hip_bf16.h>
#include <math.h>

// Problem constants
#define BB 32
#define SS 744
#define DD 512
#define HH 8
#define HDD 64
#define LL 4
#define EXPAND 4
#define NROWS (BB * SS)            // 23808
#define MROWS (NROWS * HH)         // 190464 = 1488 * 128
#define NBUF ((size_t)NROWS * DD)  // 12,189,696 floats per [B,S,D] buffer
#define SQRT_D 22.62741699796952f
#define QSCALE 0.18033688011112042f   // 0.125 * log2(e): softmax in log2 domain
#define VTS 768                    // padded (and key-permuted) vt row length

typedef __hip_bfloat16 bf16;
typedef __attribute__((ext_vector_type(8))) __bf16 bf16x8;
typedef __attribute__((ext_vector_type(4))) float f32x4;

#define GPTR(p) (const __attribute__((address_space(1))) void*)(p)
#define LPTR(p) (__attribute__((address_space(3))) void*)(p)

// XOR-swizzle: lane l stages global chunk ((l&3)^((l>>3)&3)) of local row l>>2
// into contiguous LDS slot l. Frag read of (row fr, chunk fq) is then at
// physical chunk fq^((fr>>1)&3): bank-starts span 8 groups -> 2-way (free).

// ---------------------------------------------------------------------------
// Embedding + positional encoding; writes fp32 h and bf16 h16
// ---------------------------------------------------------------------------
__global__ __launch_bounds__(128) void k_embed(const int* __restrict__ x,
                                               const float* __restrict__ emb,
                                               const float* __restrict__ pe,
                                               float* __restrict__ h,
                                               bf16* __restrict__ h16) {
    int row = blockIdx.x;
    int s = row % SS;
    int tok = x[row];
    int t = threadIdx.x;
    float4 e = ((const float4*)(emb + (size_t)tok * DD))[t];
    float4 p = ((const float4*)(pe + (size_t)s * DD))[t];
    float4 o;
    o.x = e.x * SQRT_D + p.x;
    o.y = e.y * SQRT_D + p.y;
    o.z = e.z * SQRT_D + p.z;
    o.w = e.w * SQRT_D + p.w;
    ((float4*)(h + (size_t)row * DD))[t] = o;
    bf16 b0 = __float2bfloat16(o.x), b1 = __float2bfloat16(o.y);
    bf16 b2 = __float2bfloat16(o.z), b3 = __float2bfloat16(o.w);
    ushort4 u;
    u.x = *(unsigned short*)&b0; u.y = *(unsigned short*)&b1;
    u.z = *(unsigned short*)&b2; u.w = *(unsigned short*)&b3;
    ((ushort4*)(h16 + (size_t)row * DD))[t] = u;
}

// ---------------------------------------------------------------------------
// fp32 -> bf16 conversion (grid-stride)
// ---------------------------------------------------------------------------
__global__ __launch_bounds__(256) void k_f2b(const float* __restrict__ in,
                                             bf16* __restrict__ out, int n) {
    for (int i = blockIdx.x * 256 + threadIdx.x; i < n; i += gridDim.x * 256)
        out[i] = __float2bfloat16(in[i]);
}

// ---------------------------------------------------------------------------
// All-layer QKV weight pack: Wq/Wk/Wv [L][64][64] fp32 -> wqkv [L][192][64]
// bf16, one preamble launch.  grid (16, L).
// ---------------------------------------------------------------------------
__global__ __launch_bounds__(256) void k_qkvw_all(const float* __restrict__ q,
                                                  const float* __restrict__ k,
                                                  const float* __restrict__ v,
                                                  bf16* __restrict__ out) {
    int l = blockIdx.y;
    int i = blockIdx.x * 256 + threadIdx.x;   // 0..4095
    bf16* o = out + (size_t)l * 12288;
    const size_t off = (size_t)l * 4096 + i;
    o[i]        = __float2bfloat16(q[off]);
    o[i + 4096] = __float2bfloat16(k[off]);
    o[i + 8192] = __float2bfloat16(v[off]);
}

// ---------------------------------------------------------------------------
// QKV projection as one MFMA GEMM: A = h16 as [(b,s,h)][64], W = [192][64]
// q columns (0-63) pre-scaled by 0.125*log2(e).
// ---------------------------------------------------------------------------
__global__ __launch_bounds__(256) void k_qkv_mfma(const bf16* __restrict__ A,
                                                  const bf16* __restrict__ Wqkv,
                                                  bf16* __restrict__ qk,
                                                  bf16* __restrict__ v) {
    __shared__ __align__(16) bf16 As[2][128][32];
    __shared__ __align__(16) bf16 Ws[2][192][32];
    int t = threadIdx.x;
    int w = t >> 6, lane = t & 63;
    int fr = lane & 15, fq = lane >> 4;
    int m0 = blockIdx.x * 128;
    int wm = (w >> 1) * 64;        // row half
    int wc = (w & 1) * 96;         // col half
    int lr = lane >> 2;
    int csw = ((lane & 3) ^ ((lane >> 3) & 3)) * 8;   // swizzled global chunk
    int swz8 = (fq ^ ((fr >> 1) & 3)) * 8;            // swizzled frag-read col

#pragma unroll
    for (int kc = 0; kc < 2; kc++)
#pragma unroll
        for (int i = 0; i < 2; i++) {
            int rb = w * 32 + i * 16;
            __builtin_amdgcn_global_load_lds(
                GPTR(A + (size_t)(m0 + rb + lr) * 64 + kc * 32 + csw),
                LPTR(&As[kc][rb][0]), 16, 0, 0);
        }
#pragma unroll
    for (int kc = 0; kc < 2; kc++)
#pragma unroll
        for (int i = 0; i < 3; i++) {
            int rb = w * 48 + i * 16;
            __builtin_amdgcn_global_load_lds(
                GPTR(Wqkv + (size_t)(rb + lr) * 64 + kc * 32 + csw),
                LPTR(&Ws[kc][rb][0]), 16, 0, 0);
        }
    __syncthreads();

    bf16x8 af[2][4], bw[2][6];
#pragma unroll
    for (int kc = 0; kc < 2; kc++) {
#pragma unroll
        for (int mi = 0; mi < 4; mi++)
            af[kc][mi] = *(const bf16x8*)&As[kc][wm + mi * 16 + fr][swz8];
#pragma unroll
        for (int ni = 0; ni < 6; ni++)
            bw[kc][ni] = *(const bf16x8*)&Ws[kc][wc + ni * 16 + fr][swz8];
    }
    f32x4 acc[4][6] = {};
#pragma unroll
    for (int mi = 0; mi < 4; mi++)
#pragma unroll
        for (int ni = 0; ni < 6; ni++) {
            acc[mi][ni] = __builtin_amdgcn_mfma_f32_16x16x32_bf16(af[0][mi], bw[0][ni], acc[mi][ni], 0, 0, 0);
            acc[mi][ni] = __builtin_amdgcn_mfma_f32_16x16x32_bf16(af[1][mi], bw[1][ni], acc[mi][ni], 0, 0, 0);
        }

#pragma unroll
    for (int mi = 0; mi < 4; mi++)
#pragma unroll
        for (int r = 0; r < 4; r++) {
            size_t mg = m0 + wm + mi * 16 + fq * 4 + r;
#pragma unroll
            for (int ni = 0; ni < 6; ni++) {
                int col = wc + ni * 16 + fr;
                float fv = acc[mi][ni][r];
                if (col < 64) fv *= QSCALE;
                bf16 val = __float2bfloat16(fv);
                if (col < 128) qk[mg * 128 + col] = val;
                else           v[mg * 64 + (col - 128)] = val;
            }
        }
}

// ---------------------------------------------------------------------------
// V transpose + key-permute: v [(b,s,h)][64] -> vt [bh*64 + d][768].
// Within each 32-key block, output pos 8*fq + j holds key 16*(j>>2)+4*fq+(j&3).
// grid (256, 12).
// ---------------------------------------------------------------------------
__global__ __launch_bounds__(256) void k_vt(const bf16* __restrict__ v,
                                            bf16* __restrict__ vt) {
    int bh = blockIdx.x, st = blockIdx.y;
    int b = bh >> 3, h = bh & 7;
    int t = threadIdx.x;
    __shared__ bf16 Ls[64][72];
    int s0 = st * 64;
    for (int j = t; j < 512; j += 256) {
        int si = j >> 3, e8 = (j & 7) * 8;
        int s = s0 + si; if (s > SS - 1) s = SS - 1;
        bf16x8 val = *(const bf16x8*)(v + ((size_t)(b * SS + s) * 8 + h) * 64 + e8);
        *(bf16x8*)&Ls[si][e8] = val;
    }
    __syncthreads();
    for (int j = t; j < 512; j += 256) {
        int d = j >> 3, o8 = (j & 7) * 8;       // output chunk base (0..56)
        int half = o8 & 32, fqv = (o8 & 31) >> 3;
        __align__(16) bf16 tmp[8];
#pragma unroll
        for (int i = 0; i < 8; i++)
            tmp[i] = Ls[half + 4 * fqv + 16 * (i >> 2) + (i & 3)][d];
        *(bf16x8*)(vt + ((size_t)bh * 64 + d) * VTS + s0 + o8) = *(bf16x8*)tmp;
    }
}

// ---------------------------------------------------------------------------
// Flash MFMA attention (harness-proven round-5 kernel, unchanged).
// grid (256 bh, 3 q-tiles of 256). Per block: 4 waves x 64 q-rows.
// ---------------------------------------------------------------------------
__global__ __launch_bounds__(256) void k_attn_mfma(const bf16* __restrict__ qk,
                                                   const bf16* __restrict__ vt,
                                                   bf16* __restrict__ ao) {
    int bh = blockIdx.x, qt = blockIdx.y;
    int b = bh >> 3, h = bh & 7;
    int t = threadIdx.x;
    int w = t >> 6, lane = t & 63;
    int fr = lane & 15, fq = lane >> 4;
    int lr = lane >> 2;
    int csw = ((lane & 3) ^ ((lane >> 3) & 3)) * 8;   // swizzled global chunk
    int swz8 = (fq ^ ((fr >> 1) & 3)) * 8;            // swizzled frag-read col
    int q0 = qt * 256;

    __shared__ __align__(16) bf16 Ks[2][2][64][32];   // [buf][slice][key][e]
    __shared__ __align__(16) bf16 Vs[2][2][64][32];   // [buf][slice][d][keypos]

    // Q fragments direct from global (once per block): B-frag Q[qrow][e]
    bf16x8 qf[4][2];
#pragma unroll
    for (int qs = 0; qs < 4; qs++) {
        int row = q0 + w * 64 + qs * 16 + fr;
        if (row > SS - 1) row = SS - 1;
        size_t gb = ((size_t)(b * SS + row) * 8 + h) * 128;
        qf[qs][0] = *(const bf16x8*)(qk + gb + fq * 8);
        qf[qs][1] = *(const bf16x8*)(qk + gb + 32 + fq * 8);
    }

    f32x4 o_acc[4][4] = {};                 // [qset][d-tile]
    float l_[4] = {0.f, 0.f, 0.f, 0.f};     // per-lane partial denominators

    auto STAGE = [&](int buf, int kt) {
        int k0 = kt * 64;
        int krow = k0 + w * 16 + lr; if (krow > SS - 1) krow = SS - 1;
        size_t kgb = ((size_t)(b * SS + krow) * 8 + h) * 128 + 64;
        size_t vgb = ((size_t)bh * 64 + w * 16 + lr) * VTS + k0;
#pragma unroll
        for (int p = 0; p < 2; p++) {
            __builtin_amdgcn_global_load_lds(GPTR(qk + kgb + p * 32 + csw),
                                             LPTR(&Ks[buf][p][w * 16][0]), 16, 0, 0);
            __builtin_amdgcn_global_load_lds(GPTR(vt + vgb + p * 32 + csw),
                                             LPTR(&Vs[buf][p][w * 16][0]), 16, 0, 0);
        }
    };

    STAGE(0, 0);
    for (int kt = 0; kt < 12; kt++) {
        int cur = kt & 1;
        __syncthreads();
        if (kt < 11) STAGE(cur ^ 1, kt + 1);   // fire-and-forget prefetch

        // K fragments: A[m=key][k=e], shared across all q-sets
        bf16x8 kf[4][2];
#pragma unroll
        for (int n = 0; n < 4; n++) {
            kf[n][0] = *(const bf16x8*)&Ks[cur][0][n * 16 + fr][swz8];
            kf[n][1] = *(const bf16x8*)&Ks[cur][1][n * 16 + fr][swz8];
        }

        bf16x8 pf[4][2];                      // [qset][key-slice]
#pragma unroll
        for (int qs = 0; qs < 4; qs++) {
            // S^T tiles (log2-domain scores; Q pre-scaled)
            f32x4 st[4] = {};
            __builtin_amdgcn_s_setprio(1);
#pragma unroll
            for (int n = 0; n < 4; n++) {
                st[n] = __builtin_amdgcn_mfma_f32_16x16x32_bf16(kf[n][0], qf[qs][0], st[n], 0, 0, 0);
                st[n] = __builtin_amdgcn_mfma_f32_16x16x32_bf16(kf[n][1], qf[qs][1], st[n], 0, 0, 0);
            }
            __builtin_amdgcn_s_setprio(0);
            if (kt == 11) {   // mask invalid keys (uniform branch, last tile only)
#pragma unroll
                for (int n = 0; n < 4; n++) {
                    int kb = 704 + n * 16 + fq * 4;
#pragma unroll
                    for (int r = 0; r < 4; r++)
                        if (kb + r >= SS) st[n][r] = -1e30f;
                }
            }
            // fixed-max softmax numerator: P = exp2(st); accumulate local l
            float ls = 0.f;
#pragma unroll
            for (int n = 0; n < 4; n++)
#pragma unroll
                for (int r = 0; r < 4; r++) {
                    float p = __builtin_amdgcn_exp2f(st[n][r]);
                    st[n][r] = p;
                    ls += p;
                }
            l_[qs] += ls;
            // in-lane repack to PV B-frags (key-permuted vt makes this exact)
            bf16x8 t0, t1;
#pragma unroll
            for (int e = 0; e < 4; e++) {
                t0[e]     = (__bf16)st[0][e];
                t0[e + 4] = (__bf16)st[1][e];
                t1[e]     = (__bf16)st[2][e];
                t1[e + 4] = (__bf16)st[3][e];
            }
            pf[qs][0] = t0;
            pf[qs][1] = t1;
        }

        // PV: O^T += V^T · P  (A = V-frag swizzled+key-permuted, B = in-reg P)
        __builtin_amdgcn_s_setprio(1);
#pragma unroll
        for (int dt = 0; dt < 4; dt++) {
            bf16x8 vf0 = *(const bf16x8*)&Vs[cur][0][dt * 16 + fr][swz8];
            bf16x8 vf1 = *(const bf16x8*)&Vs[cur][1][dt * 16 + fr][swz8];
#pragma unroll
            for (int qs = 0; qs < 4; qs++) {
                o_acc[qs][dt] = __builtin_amdgcn_mfma_f32_16x16x32_bf16(vf0, pf[qs][0], o_acc[qs][dt], 0, 0, 0);
                o_acc[qs][dt] = __builtin_amdgcn_mfma_f32_16x16x32_bf16(vf1, pf[qs][1], o_acc[qs][dt], 0, 0, 0);
            }
        }
        __builtin_amdgcn_s_setprio(0);
    }

    // epilogue: O^T C-layout row=d=dt*16+fq*4+r, col=qrow -> ao[s][h*64+d]
#pragma unroll
    for (int qs = 0; qs < 4; qs++) {
        int srow = q0 + w * 64 + qs * 16 + fr;
        if (srow < SS) {
            float lt = l_[qs];
            lt += __shfl_xor(lt, 16);
            lt += __shfl_xor(lt, 32);
            float inv = 1.f / lt;
            bf16* dst = ao + ((size_t)(b * SS + srow) * 8 + h) * 64;
#pragma unroll
            for (int dt = 0; dt < 4; dt++) {
                __align__(8) bf16 tb[4];
#pragma unroll
                for (int r = 0; r < 4; r++)
                    tb[r] = __float2bfloat16(o_acc[qs][dt][r] * inv);
                *(unsigned long long*)(dst + dt * 16 + fq * 4) =
                    *(unsigned long long*)tb;
            }
        }
    }
}

// ---------------------------------------------------------------------------
// bf16 MFMA GEMM: C = act(A[M,K] @ W[N,K]^T + b)
//  - BK=64 on the round-2-proven 2-phase double-buffer sync structure.
//    Same __syncthreads semantics, same staging involution applied to two
//    32-col planes per buffer (each plane's layout identical to the proven
//    BK=32 kernel).  Halves the per-K-step vmcnt(0) drains: K=512 16->8,
//    K=2048 64->32.  LDS = 2 bufs x 2 planes x (A+B) x 8 KB = 64 KB static.
//  - grid (N/128, M/128) n-fastest; XCD-chunked swizzle (nwg % 8 == 0).
// ---------------------------------------------------------------------------
template <bool RELU, bool OUT_BF16>
__global__ __launch_bounds__(256) void k_gemm_mfma(const bf16* __restrict__ A,
                                                   const bf16* __restrict__ W,
                                                   const float* __restrict__ bias,
                                                   void* __restrict__ Cout,
                                                   int M, int N, int K) {
    __shared__ __align__(16) bf16 As[2][2][128 * 32];   // [buf][kc-plane]
    __shared__ __align__(16) bf16 Ws[2][2][128 * 32];
    int t = threadIdx.x;
    int wave = t >> 6, lane = t & 63;
    // XCD-chunked bijective remap (requires gridDim.x*gridDim.y % 8 == 0)
    int nbx = gridDim.x;
    int nwg = nbx * gridDim.y;
    int bid = blockIdx.y * nbx + blockIdx.x;
    int cpx = nwg >> 3;
    int swz = (bid & 7) * cpx + (bid >> 3);
    int n0 = (swz % nbx) * 128;
    int m0 = (swz / nbx) * 128;
    int wm = (wave >> 1) * 64, wn = (wave & 1) * 64;
    int fr = lane & 15, fq = lane >> 4;
    int csw = ((lane & 3) ^ ((lane >> 3) & 3)) * 8;   // swizzled global chunk
    int swz8 = (fq ^ ((fr >> 1) & 3)) * 8;            // swizzled frag-read col

    f32x4 acc[4][4] = {};

    int r0 = wave * 16 + (lane >> 2);
    int r1 = r0 + 64;

    auto STAGE = [&](int buf, int k0) {
#pragma unroll
        for (int kc = 0; kc < 2; kc++) {
            __builtin_amdgcn_global_load_lds(
                GPTR(A + (size_t)(m0 + r0) * K + k0 + kc * 32 + csw),
                LPTR((char*)&As[buf][kc][0] + (wave << 10)), 16, 0, 0);
            __builtin_amdgcn_global_load_lds(
                GPTR(A + (size_t)(m0 + r1) * K + k0 + kc * 32 + csw),
                LPTR((char*)&As[buf][kc][0] + (wave << 10) + 4096), 16, 0, 0);
            __builtin_amdgcn_global_load_lds(
                GPTR(W + (size_t)(n0 + r0) * K + k0 + kc * 32 + csw),
                LPTR((char*)&Ws[buf][kc][0] + (wave << 10)), 16, 0, 0);
            __builtin_amdgcn_global_load_lds(
                GPTR(W + (size_t)(n0 + r1) * K + k0 + kc * 32 + csw),
                LPTR((char*)&Ws[buf][kc][0] + (wave << 10) + 4096), 16, 0, 0);
        }
    };

    int nk = K >> 6;
    STAGE(0, 0);
    for (int kt = 0; kt < nk; kt++) {
        int cur = kt & 1;
        // __syncthreads' implicit vmcnt(0)/lgkmcnt(0) drain: buf[cur] loads
        // landed (issued one compute phase ago); all waves done with buf[cur^1].
        __syncthreads();
        if (kt + 1 < nk) STAGE(cur ^ 1, (kt + 1) << 6);

        bf16x8 af[2][4], bfr[2][4];
#pragma unroll
        for (int kc = 0; kc < 2; kc++) {
#pragma unroll
            for (int i = 0; i < 4; i++)
                af[kc][i] = *(const bf16x8*)(&As[cur][kc][0] + (wm + i * 16 + fr) * 32 + swz8);
#pragma unroll
            for (int i = 0; i < 4; i++)
                bfr[kc][i] = *(const bf16x8*)(&Ws[cur][kc][0] + (wn + i * 16 + fr) * 32 + swz8);
        }
#pragma unroll
        for (int mi = 0; mi < 4; mi++)
#pragma unroll
            for (int ni = 0; ni < 4; ni++) {
                acc[mi][ni] = __builtin_amdgcn_mfma_f32_16x16x32_bf16(
                    af[0][mi], bfr[0][ni], acc[mi][ni], 0, 0, 0);
                acc[mi][ni] = __builtin_amdgcn_mfma_f32_16x16x32_bf16(
                    af[1][mi], bfr[1][ni], acc[mi][ni], 0, 0, 0);
            }
    }

    float bv[4];
#pragma unroll
    for (int ni = 0; ni < 4; ni++) bv[ni] = bias[n0 + wn + ni * 16 + fr];
#pragma unroll
    for (int mi = 0; mi < 4; mi++) {
#pragma unroll
        for (int r = 0; r < 4; r++) {
            int mg = m0 + wm + mi * 16 + fq * 4 + r;
#pragma unroll
            for (int ni = 0; ni < 4; ni++) {
                float val = acc[mi][ni][r] + bv[ni];
                if (RELU) val = fmaxf(val, 0.f);
                int ng = n0 + wn + ni * 16 + fr;
                if (OUT_BF16)
                    ((bf16*)Cout)[(size_t)mg * N + ng] = __float2bfloat16(val);
                else
                    ((float*)Cout)[(size_t)mg * N + ng] = val;
            }
        }
    }
}

// ---------------------------------------------------------------------------
// Fused residual add + LayerNorm.
// BRES16: residual `bres` is bf16 (else fp32). WF32: also write fp32 out.
// ---------------------------------------------------------------------------
template <bool BRES16, bool WF32>
__global__ __launch_bounds__(128) void k_add_ln(const float* __restrict__ a,
                                                const void* __restrict__ bres,
                                                const float* __restrict__ w,
                                                const float* __restrict__ bias,
                                                float* out,
                                                bf16* __restrict__ out16) {
    int row = blockIdx.x;
    int t = threadIdx.x;
    float4 xa = ((const float4*)(a + (size_t)row * DD))[t];
    float4 xb;
    if (BRES16) {
        ushort4 ub = ((const ushort4*)((const bf16*)bres + (size_t)row * DD))[t];
        xb.x = __bfloat162float(*(bf16*)&ub.x);
        xb.y = __bfloat162float(*(bf16*)&ub.y);
        xb.z = __bfloat162float(*(bf16*)&ub.z);
        xb.w = __bfloat162float(*(bf16*)&ub.w);
    } else {
        xb = ((const float4*)((const float*)bres + (size_t)row * DD))[t];
    }
    float4 vv;
    vv.x = xa.x + xb.x; vv.y = xa.y + xb.y;
    vv.z = xa.z + xb.z; vv.w = xa.w + xb.w;
    float s  = vv.x + vv.y + vv.z + vv.w;
    float sq = vv.x * vv.x + vv.y * vv.y + vv.z * vv.z + vv.w * vv.w;
#pragma unroll
    for (int off = 32; off > 0; off >>= 1) {
        s  += __shfl_down(s, off);
        sq += __shfl_down(sq, off);
    }
    __shared__ float red[4];
    if ((t & 63) == 0) { red[(t >> 6) * 2] = s; red[(t >> 6) * 2 + 1] = sq; }
    __syncthreads();
    float S1 = red[0] + red[2], S2 = red[1] + red[3];
    float mean = S1 * (1.f / DD);
    float var  = S2 * (1.f / DD) - mean * mean;
    float inv  = rsqrtf(var + 1e-5f);
    float4 wv = ((const float4*)w)[t];
    float4 bv = ((const float4*)bias)[t];
    float4 o;
    o.x = (vv.x - mean) * inv * wv.x + bv.x;
    o.y = (vv.y - mean) * inv * wv.y + bv.y;
    o.z = (vv.z - mean) * inv * wv.z + bv.z;
    o.w = (vv.w - mean) * inv * wv.w + bv.w;
    if (WF32)
        ((float4*)(out + (size_t)row * DD))[t] = o;
    bf16 h0 = __float2bfloat16(o.x), h1 = __float2bfloat16(o.y);
    bf16 h2 = __float2bfloat16(o.z), h3 = __float2bfloat16(o.w);
    ushort4 u;
    u.x = *(unsigned short*)&h0; u.y = *(unsigned short*)&h1;
    u.z = *(unsigned short*)&h2; u.w = *(unsigned short*)&h3;
    ((ushort4*)(out16 + (size_t)row * DD))[t] = u;
}

// ---------------------------------------------------------------------------
extern "C" void kernel_launch(void* const* d_in, const int* in_sizes, int n_in,
                              void* d_out, int out_size, void* d_ws, size_t ws_size,
                              hipStream_t stream) {
    const int*   x    = (const int*)d_in[0];
    const float* emb  = (const float*)d_in[1];
    const float* pe   = (const float*)d_in[2];
    const float* Wq   = (const float*)d_in[3];
    const float* Wk   = (const float*)d_in[4];
    const float* Wv   = (const float*)d_in[5];
    const float* Wo   = (const float*)d_in[6];
    const float* bo   = (const float*)d_in[7];
    const float* ln1w = (const float*)d_in[8];
    const float* ln1b = (const float*)d_in[9];
    const float* W1   = (const float*)d_in[10];
    const float* b1   = (const float*)d_in[11];
    const float* W2   = (const float*)d_in[12];
    const float* b2   = (const float*)d_in[13];
    const float* ln2w = (const float*)d_in[14];
    const float* ln2b = (const float*)d_in[15];

    float* h  = (float*)d_out;
    float* ws = (float*)d_ws;
    // Region A [0, NBUF): qk bf16 [MROWS][128] -> wo_out fp32 -> ff fp32
    bf16*  qkbuf  = (bf16*)ws;
    float* wo_out = ws;
    float* ff     = ws;
    // Region B+C [NBUF, 3*NBUF): v/vt (dead after attn) -> f1b bf16 [23808][2048]
    bf16*  v_buf  = (bf16*)(ws + NBUF);
    bf16*  vt_buf = (bf16*)(ws + NBUF + NBUF / 2);
    bf16*  f1b    = (bf16*)(ws + NBUF);
    // Region D [3*NBUF, 3.5*NBUF): aob -> n1b (bf16 [NROWS][512])
    bf16*  regD   = (bf16*)(ws + 3 * NBUF);
    // Region E [3.5*NBUF, 4*NBUF): h16
    bf16*  h16    = regD + NBUF;
    // Weights (bf16)
    bf16*  wob16  = h16 + NBUF;
    bf16*  w1b16  = wob16 + (size_t)LL * DD * DD;
    bf16*  w2b16  = w1b16 + (size_t)LL * EXPAND * DD * DD;
    bf16*  wqkvA  = w2b16 + (size_t)LL * DD * EXPAND * DD;   // [L][192][64]

    k_f2b<<<2048, 256, 0, stream>>>(Wo, wob16, LL * DD * DD);
    k_f2b<<<4096, 256, 0, stream>>>(W1, w1b16, LL * EXPAND * DD * DD);
    k_f2b<<<4096, 256, 0, stream>>>(W2, w2b16, LL * EXPAND * DD * DD);
    k_qkvw_all<<<dim3(16, LL), 256, 0, stream>>>(Wq, Wk, Wv, wqkvA);
    k_embed<<<NROWS, 128, 0, stream>>>(x, emb, pe, h, h16);

    for (int l = 0; l < LL; l++) {
        k_qkv_mfma<<<MROWS / 128, 256, 0, stream>>>(h16, wqkvA + (size_t)l * 12288,
                                                    qkbuf, v_buf);
        k_vt<<<dim3(256, 12), 256, 0, stream>>>(v_buf, vt_buf);
        k_attn_mfma<<<dim3(256, 3), 256, 0, stream>>>(qkbuf, vt_buf, regD);
        k_gemm_mfma<false, false><<<dim3(DD / 128, NROWS / 128), 256, 0, stream>>>(
            regD, wob16 + (size_t)l * DD * DD, bo + (size_t)l * DD, wo_out,
            NROWS, DD, DD);
        // n1 kept only as bf16 (regD); frees region C for full-size f1b
        k_add_ln<false, false><<<NROWS, 128, 0, stream>>>(wo_out, h,
            ln1w + (size_t)l * DD, ln1b + (size_t)l * DD, nullptr, regD);
        k_gemm_mfma<true, true><<<dim3((EXPAND * DD) / 128, NROWS / 128), 256, 0, stream>>>(
            regD, w1b16 + (size_t)l * EXPAND * DD * DD, b1 + (size_t)l * EXPAND * DD,
            f1b, NROWS, EXPAND * DD, DD);
        k_gemm_mfma<false, false><<<dim3(DD / 128, NROWS / 128), 256, 0, stream>>>(
            f1b, w2b16 + (size_t)l * DD * EXPAND * DD, b2 + (size_t)l * DD,
            ff, NROWS, DD, EXPAND * DD);
        k_add_ln<true, true><<<NROWS, 128, 0, stream>>>(ff, regD,
            ln2w + (size_t)l * DD, ln2b + (size_t)l * DD, h, h16);
    }
}

// Round 9
// 1192.246 us; speedup vs baseline: 1.1024x; 1.1024x over previous
//
#include <hip/hip_runtime.h>
#include <hip/hip_bf16.h>
#include <math.h>

// Problem constants
#define BB 32
#define SS 744
#define DD 512
#define HH 8
#define HDD 64
#define LL 4
#define EXPAND 4
#define NROWS (BB * SS)            // 23808
#define MROWS (NROWS * HH)         // 190464 = 1488 * 128
#define NBUF ((size_t)NROWS * DD)  // 12,189,696 floats per [B,S,D] buffer
#define SQRT_D 22.62741699796952f
#define QSCALE 0.18033688011112042f   // 0.125 * log2(e): softmax in log2 domain
#define VTS 768                    // padded (and key-permuted) vt row length

typedef __hip_bfloat16 bf16;
typedef __attribute__((ext_vector_type(8))) __bf16 bf16x8;
typedef __attribute__((ext_vector_type(4))) float f32x4;

#define GPTR(p) (const __attribute__((address_space(1))) void*)(p)
#define LPTR(p) (__attribute__((address_space(3))) void*)(p)

// XOR-swizzle: lane l stages global chunk ((l&3)^((l>>3)&3)) of local row l>>2
// into contiguous LDS slot l. Frag read of (row fr, chunk fq) is then at
// physical chunk fq^((fr>>1)&3): bank-starts span 8 groups -> 2-way (free).

// ---------------------------------------------------------------------------
// Embedding + positional encoding; writes fp32 h and bf16 h16
// ---------------------------------------------------------------------------
__global__ __launch_bounds__(128) void k_embed(const int* __restrict__ x,
                                               const float* __restrict__ emb,
                                               const float* __restrict__ pe,
                                               float* __restrict__ h,
                                               bf16* __restrict__ h16) {
    int row = blockIdx.x;
    int s = row % SS;
    int tok = x[row];
    int t = threadIdx.x;
    float4 e = ((const float4*)(emb + (size_t)tok * DD))[t];
    float4 p = ((const float4*)(pe + (size_t)s * DD))[t];
    float4 o;
    o.x = e.x * SQRT_D + p.x;
    o.y = e.y * SQRT_D + p.y;
    o.z = e.z * SQRT_D + p.z;
    o.w = e.w * SQRT_D + p.w;
    ((float4*)(h + (size_t)row * DD))[t] = o;
    bf16 b0 = __float2bfloat16(o.x), b1 = __float2bfloat16(o.y);
    bf16 b2 = __float2bfloat16(o.z), b3 = __float2bfloat16(o.w);
    ushort4 u;
    u.x = *(unsigned short*)&b0; u.y = *(unsigned short*)&b1;
    u.z = *(unsigned short*)&b2; u.w = *(unsigned short*)&b3;
    ((ushort4*)(h16 + (size_t)row * DD))[t] = u;
}

// ---------------------------------------------------------------------------
// fp32 -> bf16 conversion (grid-stride)
// ---------------------------------------------------------------------------
__global__ __launch_bounds__(256) void k_f2b(const float* __restrict__ in,
                                             bf16* __restrict__ out, int n) {
    for (int i = blockIdx.x * 256 + threadIdx.x; i < n; i += gridDim.x * 256)
        out[i] = __float2bfloat16(in[i]);
}

// ---------------------------------------------------------------------------
// All-layer QKV weight pack: Wq/Wk/Wv [L][64][64] fp32 -> wqkv [L][192][64]
// bf16, one preamble launch.  grid (16, L).
// ---------------------------------------------------------------------------
__global__ __launch_bounds__(256) void k_qkvw_all(const float* __restrict__ q,
                                                  const float* __restrict__ k,
                                                  const float* __restrict__ v,
                                                  bf16* __restrict__ out) {
    int l = blockIdx.y;
    int i = blockIdx.x * 256 + threadIdx.x;   // 0..4095
    bf16* o = out + (size_t)l * 12288;
    const size_t off = (size_t)l * 4096 + i;
    o[i]        = __float2bfloat16(q[off]);
    o[i + 4096] = __float2bfloat16(k[off]);
    o[i + 8192] = __float2bfloat16(v[off]);
}

// ---------------------------------------------------------------------------
// QKV projection as one MFMA GEMM: A = h16 as [(b,s,h)][64], W = [192][64]
// q columns (0-63) pre-scaled by 0.125*log2(e).
// ---------------------------------------------------------------------------
__global__ __launch_bounds__(256) void k_qkv_mfma(const bf16* __restrict__ A,
                                                  const bf16* __restrict__ Wqkv,
                                                  bf16* __restrict__ qk,
                                                  bf16* __restrict__ v) {
    __shared__ __align__(16) bf16 As[2][128][32];
    __shared__ __align__(16) bf16 Ws[2][192][32];
    int t = threadIdx.x;
    int w = t >> 6, lane = t & 63;
    int fr = lane & 15, fq = lane >> 4;
    int m0 = blockIdx.x * 128;
    int wm = (w >> 1) * 64;        // row half
    int wc = (w & 1) * 96;         // col half
    int lr = lane >> 2;
    int csw = ((lane & 3) ^ ((lane >> 3) & 3)) * 8;   // swizzled global chunk
    int swz8 = (fq ^ ((fr >> 1) & 3)) * 8;            // swizzled frag-read col

#pragma unroll
    for (int kc = 0; kc < 2; kc++)
#pragma unroll
        for (int i = 0; i < 2; i++) {
            int rb = w * 32 + i * 16;
            __builtin_amdgcn_global_load_lds(
                GPTR(A + (size_t)(m0 + rb + lr) * 64 + kc * 32 + csw),
                LPTR(&As[kc][rb][0]), 16, 0, 0);
        }
#pragma unroll
    for (int kc = 0; kc < 2; kc++)
#pragma unroll
        for (int i = 0; i < 3; i++) {
            int rb = w * 48 + i * 16;
            __builtin_amdgcn_global_load_lds(
                GPTR(Wqkv + (size_t)(rb + lr) * 64 + kc * 32 + csw),
                LPTR(&Ws[kc][rb][0]), 16, 0, 0);
        }
    __syncthreads();

    bf16x8 af[2][4], bw[2][6];
#pragma unroll
    for (int kc = 0; kc < 2; kc++) {
#pragma unroll
        for (int mi = 0; mi < 4; mi++)
            af[kc][mi] = *(const bf16x8*)&As[kc][wm + mi * 16 + fr][swz8];
#pragma unroll
        for (int ni = 0; ni < 6; ni++)
            bw[kc][ni] = *(const bf16x8*)&Ws[kc][wc + ni * 16 + fr][swz8];
    }
    f32x4 acc[4][6] = {};
#pragma unroll
    for (int mi = 0; mi < 4; mi++)
#pragma unroll
        for (int ni = 0; ni < 6; ni++) {
            acc[mi][ni] = __builtin_amdgcn_mfma_f32_16x16x32_bf16(af[0][mi], bw[0][ni], acc[mi][ni], 0, 0, 0);
            acc[mi][ni] = __builtin_amdgcn_mfma_f32_16x16x32_bf16(af[1][mi], bw[1][ni], acc[mi][ni], 0, 0, 0);
        }

#pragma unroll
    for (int mi = 0; mi < 4; mi++)
#pragma unroll
        for (int r = 0; r < 4; r++) {
            size_t mg = m0 + wm + mi * 16 + fq * 4 + r;
#pragma unroll
            for (int ni = 0; ni < 6; ni++) {
                int col = wc + ni * 16 + fr;
                float fv = acc[mi][ni][r];
                if (col < 64) fv *= QSCALE;
                bf16 val = __float2bfloat16(fv);
                if (col < 128) qk[mg * 128 + col] = val;
                else           v[mg * 64 + (col - 128)] = val;
            }
        }
}

// ---------------------------------------------------------------------------
// V transpose + key-permute: v [(b,s,h)][64] -> vt [bh*64 + d][768].
// Within each 32-key block, output pos 8*fq + j holds key 16*(j>>2)+4*fq+(j&3).
// grid (256, 12).
// ---------------------------------------------------------------------------
__global__ __launch_bounds__(256) void k_vt(const bf16* __restrict__ v,
                                            bf16* __restrict__ vt) {
    int bh = blockIdx.x, st = blockIdx.y;
    int b = bh >> 3, h = bh & 7;
    int t = threadIdx.x;
    __shared__ bf16 Ls[64][72];
    int s0 = st * 64;
    for (int j = t; j < 512; j += 256) {
        int si = j >> 3, e8 = (j & 7) * 8;
        int s = s0 + si; if (s > SS - 1) s = SS - 1;
        bf16x8 val = *(const bf16x8*)(v + ((size_t)(b * SS + s) * 8 + h) * 64 + e8);
        *(bf16x8*)&Ls[si][e8] = val;
    }
    __syncthreads();
    for (int j = t; j < 512; j += 256) {
        int d = j >> 3, o8 = (j & 7) * 8;       // output chunk base (0..56)
        int half = o8 & 32, fqv = (o8 & 31) >> 3;
        __align__(16) bf16 tmp[8];
#pragma unroll
        for (int i = 0; i < 8; i++)
            tmp[i] = Ls[half + 4 * fqv + 16 * (i >> 2) + (i & 3)][d];
        *(bf16x8*)(vt + ((size_t)bh * 64 + d) * VTS + s0 + o8) = *(bf16x8*)tmp;
    }
}

// ---------------------------------------------------------------------------
// Flash MFMA attention (harness-proven round-5 kernel, unchanged).
// grid (256 bh, 3 q-tiles of 256). Per block: 4 waves x 64 q-rows.
// ---------------------------------------------------------------------------
__global__ __launch_bounds__(256) void k_attn_mfma(const bf16* __restrict__ qk,
                                                   const bf16* __restrict__ vt,
                                                   bf16* __restrict__ ao) {
    int bh = blockIdx.x, qt = blockIdx.y;
    int b = bh >> 3, h = bh & 7;
    int t = threadIdx.x;
    int w = t >> 6, lane = t & 63;
    int fr = lane & 15, fq = lane >> 4;
    int lr = lane >> 2;
    int csw = ((lane & 3) ^ ((lane >> 3) & 3)) * 8;   // swizzled global chunk
    int swz8 = (fq ^ ((fr >> 1) & 3)) * 8;            // swizzled frag-read col
    int q0 = qt * 256;

    __shared__ __align__(16) bf16 Ks[2][2][64][32];   // [buf][slice][key][e]
    __shared__ __align__(16) bf16 Vs[2][2][64][32];   // [buf][slice][d][keypos]

    // Q fragments direct from global (once per block): B-frag Q[qrow][e]
    bf16x8 qf[4][2];
#pragma unroll
    for (int qs = 0; qs < 4; qs++) {
        int row = q0 + w * 64 + qs * 16 + fr;
        if (row > SS - 1) row = SS - 1;
        size_t gb = ((size_t)(b * SS + row) * 8 + h) * 128;
        qf[qs][0] = *(const bf16x8*)(qk + gb + fq * 8);
        qf[qs][1] = *(const bf16x8*)(qk + gb + 32 + fq * 8);
    }

    f32x4 o_acc[4][4] = {};                 // [qset][d-tile]
    float l_[4] = {0.f, 0.f, 0.f, 0.f};     // per-lane partial denominators

    auto STAGE = [&](int buf, int kt) {
        int k0 = kt * 64;
        int krow = k0 + w * 16 + lr; if (krow > SS - 1) krow = SS - 1;
        size_t kgb = ((size_t)(b * SS + krow) * 8 + h) * 128 + 64;
        size_t vgb = ((size_t)bh * 64 + w * 16 + lr) * VTS + k0;
#pragma unroll
        for (int p = 0; p < 2; p++) {
            __builtin_amdgcn_global_load_lds(GPTR(qk + kgb + p * 32 + csw),
                                             LPTR(&Ks[buf][p][w * 16][0]), 16, 0, 0);
            __builtin_amdgcn_global_load_lds(GPTR(vt + vgb + p * 32 + csw),
                                             LPTR(&Vs[buf][p][w * 16][0]), 16, 0, 0);
        }
    };

    STAGE(0, 0);
    for (int kt = 0; kt < 12; kt++) {
        int cur = kt & 1;
        __syncthreads();
        if (kt < 11) STAGE(cur ^ 1, kt + 1);   // fire-and-forget prefetch

        // K fragments: A[m=key][k=e], shared across all q-sets
        bf16x8 kf[4][2];
#pragma unroll
        for (int n = 0; n < 4; n++) {
            kf[n][0] = *(const bf16x8*)&Ks[cur][0][n * 16 + fr][swz8];
            kf[n][1] = *(const bf16x8*)&Ks[cur][1][n * 16 + fr][swz8];
        }

        bf16x8 pf[4][2];                      // [qset][key-slice]
#pragma unroll
        for (int qs = 0; qs < 4; qs++) {
            // S^T tiles (log2-domain scores; Q pre-scaled)
            f32x4 st[4] = {};
            __builtin_amdgcn_s_setprio(1);
#pragma unroll
            for (int n = 0; n < 4; n++) {
                st[n] = __builtin_amdgcn_mfma_f32_16x16x32_bf16(kf[n][0], qf[qs][0], st[n], 0, 0, 0);
                st[n] = __builtin_amdgcn_mfma_f32_16x16x32_bf16(kf[n][1], qf[qs][1], st[n], 0, 0, 0);
            }
            __builtin_amdgcn_s_setprio(0);
            if (kt == 11) {   // mask invalid keys (uniform branch, last tile only)
#pragma unroll
                for (int n = 0; n < 4; n++) {
                    int kb = 704 + n * 16 + fq * 4;
#pragma unroll
                    for (int r = 0; r < 4; r++)
                        if (kb + r >= SS) st[n][r] = -1e30f;
                }
            }
            // fixed-max softmax numerator: P = exp2(st); accumulate local l
            float ls = 0.f;
#pragma unroll
            for (int n = 0; n < 4; n++)
#pragma unroll
                for (int r = 0; r < 4; r++) {
                    float p = __builtin_amdgcn_exp2f(st[n][r]);
                    st[n][r] = p;
                    ls += p;
                }
            l_[qs] += ls;
            // in-lane repack to PV B-frags (key-permuted vt makes this exact)
            bf16x8 t0, t1;
#pragma unroll
            for (int e = 0; e < 4; e++) {
                t0[e]     = (__bf16)st[0][e];
                t0[e + 4] = (__bf16)st[1][e];
                t1[e]     = (__bf16)st[2][e];
                t1[e + 4] = (__bf16)st[3][e];
            }
            pf[qs][0] = t0;
            pf[qs][1] = t1;
        }

        // PV: O^T += V^T · P  (A = V-frag swizzled+key-permuted, B = in-reg P)
        __builtin_amdgcn_s_setprio(1);
#pragma unroll
        for (int dt = 0; dt < 4; dt++) {
            bf16x8 vf0 = *(const bf16x8*)&Vs[cur][0][dt * 16 + fr][swz8];
            bf16x8 vf1 = *(const bf16x8*)&Vs[cur][1][dt * 16 + fr][swz8];
#pragma unroll
            for (int qs = 0; qs < 4; qs++) {
                o_acc[qs][dt] = __builtin_amdgcn_mfma_f32_16x16x32_bf16(vf0, pf[qs][0], o_acc[qs][dt], 0, 0, 0);
                o_acc[qs][dt] = __builtin_amdgcn_mfma_f32_16x16x32_bf16(vf1, pf[qs][1], o_acc[qs][dt], 0, 0, 0);
            }
        }
        __builtin_amdgcn_s_setprio(0);
    }

    // epilogue: O^T C-layout row=d=dt*16+fq*4+r, col=qrow -> ao[s][h*64+d]
#pragma unroll
    for (int qs = 0; qs < 4; qs++) {
        int srow = q0 + w * 64 + qs * 16 + fr;
        if (srow < SS) {
            float lt = l_[qs];
            lt += __shfl_xor(lt, 16);
            lt += __shfl_xor(lt, 32);
            float inv = 1.f / lt;
            bf16* dst = ao + ((size_t)(b * SS + srow) * 8 + h) * 64;
#pragma unroll
            for (int dt = 0; dt < 4; dt++) {
                __align__(8) bf16 tb[4];
#pragma unroll
                for (int r = 0; r < 4; r++)
                    tb[r] = __float2bfloat16(o_acc[qs][dt][r] * inv);
                *(unsigned long long*)(dst + dt * 16 + fq * 4) =
                    *(unsigned long long*)tb;
            }
        }
    }
}

// ---------------------------------------------------------------------------
// bf16 MFMA GEMM: C = act(A[M,K] @ W[N,K]^T + b)   (round-2 proven, exact:
// BK=32, 2-phase double-buffer, 32 KB LDS — the verified local optimum).
//  - grid (N/128, M/128) n-fastest; XCD-chunked swizzle (nwg % 8 == 0).
// ---------------------------------------------------------------------------
template <bool RELU, bool OUT_BF16>
__global__ __launch_bounds__(256) void k_gemm_mfma(const bf16* __restrict__ A,
                                                   const bf16* __restrict__ W,
                                                   const float* __restrict__ bias,
                                                   void* __restrict__ Cout,
                                                   int M, int N, int K) {
    __shared__ __align__(16) bf16 As[2][128 * 32];
    __shared__ __align__(16) bf16 Ws[2][128 * 32];
    int t = threadIdx.x;
    int wave = t >> 6, lane = t & 63;
    // XCD-chunked bijective remap (requires gridDim.x*gridDim.y % 8 == 0)
    int nbx = gridDim.x;
    int nwg = nbx * gridDim.y;
    int bid = blockIdx.y * nbx + blockIdx.x;
    int cpx = nwg >> 3;
    int swz = (bid & 7) * cpx + (bid >> 3);
    int n0 = (swz % nbx) * 128;
    int m0 = (swz / nbx) * 128;
    int wm = (wave >> 1) * 64, wn = (wave & 1) * 64;
    int fr = lane & 15, fq = lane >> 4;
    int csw = ((lane & 3) ^ ((lane >> 3) & 3)) * 8;   // swizzled global chunk
    int swz8 = (fq ^ ((fr >> 1) & 3)) * 8;            // swizzled frag-read col

    f32x4 acc[4][4] = {};

    int r0 = wave * 16 + (lane >> 2);
    int r1 = r0 + 64;

    auto STAGE = [&](int buf, int k0) {
        __builtin_amdgcn_global_load_lds(GPTR(A + (size_t)(m0 + r0) * K + k0 + csw),
                                         LPTR((char*)&As[buf][0] + (wave << 10)), 16, 0, 0);
        __builtin_amdgcn_global_load_lds(GPTR(A + (size_t)(m0 + r1) * K + k0 + csw),
                                         LPTR((char*)&As[buf][0] + (wave << 10) + 4096), 16, 0, 0);
        __builtin_amdgcn_global_load_lds(GPTR(W + (size_t)(n0 + r0) * K + k0 + csw),
                                         LPTR((char*)&Ws[buf][0] + (wave << 10)), 16, 0, 0);
        __builtin_amdgcn_global_load_lds(GPTR(W + (size_t)(n0 + r1) * K + k0 + csw),
                                         LPTR((char*)&Ws[buf][0] + (wave << 10) + 4096), 16, 0, 0);
    };

    int nk = K >> 5;
    STAGE(0, 0);
    for (int kt = 0; kt < nk; kt++) {
        int cur = kt & 1;
        __syncthreads();
        if (kt + 1 < nk) STAGE(cur ^ 1, (kt + 1) << 5);

        bf16x8 af[4], bfr[4];
#pragma unroll
        for (int i = 0; i < 4; i++)
            af[i] = *(const bf16x8*)(&As[cur][0] + (wm + i * 16 + fr) * 32 + swz8);
#pragma unroll
        for (int i = 0; i < 4; i++)
            bfr[i] = *(const bf16x8*)(&Ws[cur][0] + (wn + i * 16 + fr) * 32 + swz8);
#pragma unroll
        for (int mi = 0; mi < 4; mi++)
#pragma unroll
            for (int ni = 0; ni < 4; ni++)
                acc[mi][ni] = __builtin_amdgcn_mfma_f32_16x16x32_bf16(
                    af[mi], bfr[ni], acc[mi][ni], 0, 0, 0);
    }

    float bv[4];
#pragma unroll
    for (int ni = 0; ni < 4; ni++) bv[ni] = bias[n0 + wn + ni * 16 + fr];
#pragma unroll
    for (int mi = 0; mi < 4; mi++) {
#pragma unroll
        for (int r = 0; r < 4; r++) {
            int mg = m0 + wm + mi * 16 + fq * 4 + r;
#pragma unroll
            for (int ni = 0; ni < 4; ni++) {
                float val = acc[mi][ni][r] + bv[ni];
                if (RELU) val = fmaxf(val, 0.f);
                int ng = n0 + wn + ni * 16 + fr;
                if (OUT_BF16)
                    ((bf16*)Cout)[(size_t)mg * N + ng] = __float2bfloat16(val);
                else
                    ((float*)Cout)[(size_t)mg * N + ng] = val;
            }
        }
    }
}

// ---------------------------------------------------------------------------
// Fused residual add + LayerNorm.
// AF16: `a` is bf16 (else fp32).  BRES16: residual `bres` is bf16.
// WF32: also write fp32 out.  Residual math is fp32 throughout.
// ---------------------------------------------------------------------------
template <bool AF16, bool BRES16, bool WF32>
__global__ __launch_bounds__(128) void k_add_ln(const void* __restrict__ a,
                                                const void* __restrict__ bres,
                                                const float* __restrict__ w,
                                                const float* __restrict__ bias,
                                                float* out,
                                                bf16* __restrict__ out16) {
    int row = blockIdx.x;
    int t = threadIdx.x;
    float4 xa;
    if (AF16) {
        ushort4 ua = ((const ushort4*)((const bf16*)a + (size_t)row * DD))[t];
        xa.x = __bfloat162float(*(bf16*)&ua.x);
        xa.y = __bfloat162float(*(bf16*)&ua.y);
        xa.z = __bfloat162float(*(bf16*)&ua.z);
        xa.w = __bfloat162float(*(bf16*)&ua.w);
    } else {
        xa = ((const float4*)((const float*)a + (size_t)row * DD))[t];
    }
    float4 xb;
    if (BRES16) {
        ushort4 ub = ((const ushort4*)((const bf16*)bres + (size_t)row * DD))[t];
        xb.x = __bfloat162float(*(bf16*)&ub.x);
        xb.y = __bfloat162float(*(bf16*)&ub.y);
        xb.z = __bfloat162float(*(bf16*)&ub.z);
        xb.w = __bfloat162float(*(bf16*)&ub.w);
    } else {
        xb = ((const float4*)((const float*)bres + (size_t)row * DD))[t];
    }
    float4 vv;
    vv.x = xa.x + xb.x; vv.y = xa.y + xb.y;
    vv.z = xa.z + xb.z; vv.w = xa.w + xb.w;
    float s  = vv.x + vv.y + vv.z + vv.w;
    float sq = vv.x * vv.x + vv.y * vv.y + vv.z * vv.z + vv.w * vv.w;
#pragma unroll
    for (int off = 32; off > 0; off >>= 1) {
        s  += __shfl_down(s, off);
        sq += __shfl_down(sq, off);
    }
    __shared__ float red[4];
    if ((t & 63) == 0) { red[(t >> 6) * 2] = s; red[(t >> 6) * 2 + 1] = sq; }
    __syncthreads();
    float S1 = red[0] + red[2], S2 = red[1] + red[3];
    float mean = S1 * (1.f / DD);
    float var  = S2 * (1.f / DD) - mean * mean;
    float inv  = rsqrtf(var + 1e-5f);
    float4 wv = ((const float4*)w)[t];
    float4 bv = ((const float4*)bias)[t];
    float4 o;
    o.x = (vv.x - mean) * inv * wv.x + bv.x;
    o.y = (vv.y - mean) * inv * wv.y + bv.y;
    o.z = (vv.z - mean) * inv * wv.z + bv.z;
    o.w = (vv.w - mean) * inv * wv.w + bv.w;
    if (WF32)
        ((float4*)(out + (size_t)row * DD))[t] = o;
    bf16 h0 = __float2bfloat16(o.x), h1 = __float2bfloat16(o.y);
    bf16 h2 = __float2bfloat16(o.z), h3 = __float2bfloat16(o.w);
    ushort4 u;
    u.x = *(unsigned short*)&h0; u.y = *(unsigned short*)&h1;
    u.z = *(unsigned short*)&h2; u.w = *(unsigned short*)&h3;
    ((ushort4*)(out16 + (size_t)row * DD))[t] = u;
}

// ---------------------------------------------------------------------------
extern "C" void kernel_launch(void* const* d_in, const int* in_sizes, int n_in,
                              void* d_out, int out_size, void* d_ws, size_t ws_size,
                              hipStream_t stream) {
    const int*   x    = (const int*)d_in[0];
    const float* emb  = (const float*)d_in[1];
    const float* pe   = (const float*)d_in[2];
    const float* Wq   = (const float*)d_in[3];
    const float* Wk   = (const float*)d_in[4];
    const float* Wv   = (const float*)d_in[5];
    const float* Wo   = (const float*)d_in[6];
    const float* bo   = (const float*)d_in[7];
    const float* ln1w = (const float*)d_in[8];
    const float* ln1b = (const float*)d_in[9];
    const float* W1   = (const float*)d_in[10];
    const float* b1   = (const float*)d_in[11];
    const float* W2   = (const float*)d_in[12];
    const float* b2   = (const float*)d_in[13];
    const float* ln2w = (const float*)d_in[14];
    const float* ln2b = (const float*)d_in[15];

    float* h  = (float*)d_out;
    float* ws = (float*)d_ws;
    // Region A [0, NBUF): qk bf16 [MROWS][128] -> wo16 bf16 -> ff16 bf16
    bf16*  qkbuf  = (bf16*)ws;
    bf16*  wo16   = (bf16*)ws;
    bf16*  ff16   = (bf16*)ws;
    // Region B+C [NBUF, 3*NBUF): v/vt (dead after attn) -> f1b bf16 [23808][2048]
    bf16*  v_buf  = (bf16*)(ws + NBUF);
    bf16*  vt_buf = (bf16*)(ws + NBUF + NBUF / 2);
    bf16*  f1b    = (bf16*)(ws + NBUF);
    // Region D [3*NBUF, 3.5*NBUF): aob -> n1b (bf16 [NROWS][512])
    bf16*  regD   = (bf16*)(ws + 3 * NBUF);
    // Region E [3.5*NBUF, 4*NBUF): h16
    bf16*  h16    = regD + NBUF;
    // Weights (bf16)
    bf16*  wob16  = h16 + NBUF;
    bf16*  w1b16  = wob16 + (size_t)LL * DD * DD;
    bf16*  w2b16  = w1b16 + (size_t)LL * EXPAND * DD * DD;
    bf16*  wqkvA  = w2b16 + (size_t)LL * DD * EXPAND * DD;   // [L][192][64]

    k_f2b<<<2048, 256, 0, stream>>>(Wo, wob16, LL * DD * DD);
    k_f2b<<<4096, 256, 0, stream>>>(W1, w1b16, LL * EXPAND * DD * DD);
    k_f2b<<<4096, 256, 0, stream>>>(W2, w2b16, LL * EXPAND * DD * DD);
    k_qkvw_all<<<dim3(16, LL), 256, 0, stream>>>(Wq, Wk, Wv, wqkvA);
    k_embed<<<NROWS, 128, 0, stream>>>(x, emb, pe, h, h16);

    for (int l = 0; l < LL; l++) {
        k_qkv_mfma<<<MROWS / 128, 256, 0, stream>>>(h16, wqkvA + (size_t)l * 12288,
                                                    qkbuf, v_buf);
        k_vt<<<dim3(256, 12), 256, 0, stream>>>(v_buf, vt_buf);
        k_attn_mfma<<<dim3(256, 3), 256, 0, stream>>>(qkbuf, vt_buf, regD);
        // Wo output kept bf16 (pre-LN tensor; LN renormalizes the rounding)
        k_gemm_mfma<false, true><<<dim3(DD / 128, NROWS / 128), 256, 0, stream>>>(
            regD, wob16 + (size_t)l * DD * DD, bo + (size_t)l * DD, wo16,
            NROWS, DD, DD);
        // n1 kept only as bf16 (regD); frees region C for full-size f1b
        k_add_ln<true, false, false><<<NROWS, 128, 0, stream>>>(wo16, h,
            ln1w + (size_t)l * DD, ln1b + (size_t)l * DD, nullptr, regD);
        k_gemm_mfma<true, true><<<dim3((EXPAND * DD) / 128, NROWS / 128), 256, 0, stream>>>(
            regD, w1b16 + (size_t)l * EXPAND * DD * DD, b1 + (size_t)l * EXPAND * DD,
            f1b, NROWS, EXPAND * DD, DD);
        // FF2 output kept bf16 (pre-LN tensor)
        k_gemm_mfma<false, true><<<dim3(DD / 128, NROWS / 128), 256, 0, stream>>>(
            f1b, w2b16 + (size_t)l * DD * EXPAND * DD, b2 + (size_t)l * DD,
            ff16, NROWS, DD, EXPAND * DD);
        k_add_ln<true, true, true><<<NROWS, 128, 0, stream>>>(ff16, regD,
            ln2w + (size_t)l * DD, ln2b + (size_t)l * DD, h, h16);
    }
}

// Round 10
// 1189.177 us; speedup vs baseline: 1.1052x; 1.0026x over previous
//
#include <hip/hip_runtime.h>
#include <hip/hip_bf16.h>
#include <math.h>

// Problem constants
#define BB 32
#define SS 744
#define DD 512
#define HH 8
#define HDD 64
#define LL 4
#define EXPAND 4
#define NROWS (BB * SS)            // 23808
#define MROWS (NROWS * HH)         // 190464 = 1488 * 128
#define NBUF ((size_t)NROWS * DD)  // 12,189,696 floats per [B,S,D] buffer
#define SQRT_D 22.62741699796952f
#define QSCALE 0.18033688011112042f   // 0.125 * log2(e): softmax in log2 domain
#define VTS 768                    // padded (and key-permuted) vt row length

typedef __hip_bfloat16 bf16;
typedef __attribute__((ext_vector_type(8))) __bf16 bf16x8;
typedef __attribute__((ext_vector_type(4))) float f32x4;

#define GPTR(p) (const __attribute__((address_space(1))) void*)(p)
#define LPTR(p) (__attribute__((address_space(3))) void*)(p)

// XOR-swizzle: lane l stages global chunk ((l&3)^((l>>3)&3)) of local row l>>2
// into contiguous LDS slot l. Frag read of (row fr, chunk fq) is then at
// physical chunk fq^((fr>>1)&3): bank-starts span 8 groups -> 2-way (free).

// ---------------------------------------------------------------------------
// Embedding + positional encoding; writes bf16 h16 only (the bf16 residual
// carrier).  fp32 d_out is produced once, by the last layer's ln2.
// ---------------------------------------------------------------------------
__global__ __launch_bounds__(128) void k_embed(const int* __restrict__ x,
                                               const float* __restrict__ emb,
                                               const float* __restrict__ pe,
                                               bf16* __restrict__ h16) {
    int row = blockIdx.x;
    int s = row % SS;
    int tok = x[row];
    int t = threadIdx.x;
    float4 e = ((const float4*)(emb + (size_t)tok * DD))[t];
    float4 p = ((const float4*)(pe + (size_t)s * DD))[t];
    float4 o;
    o.x = e.x * SQRT_D + p.x;
    o.y = e.y * SQRT_D + p.y;
    o.z = e.z * SQRT_D + p.z;
    o.w = e.w * SQRT_D + p.w;
    bf16 b0 = __float2bfloat16(o.x), b1 = __float2bfloat16(o.y);
    bf16 b2 = __float2bfloat16(o.z), b3 = __float2bfloat16(o.w);
    ushort4 u;
    u.x = *(unsigned short*)&b0; u.y = *(unsigned short*)&b1;
    u.z = *(unsigned short*)&b2; u.w = *(unsigned short*)&b3;
    ((ushort4*)(h16 + (size_t)row * DD))[t] = u;
}

// ---------------------------------------------------------------------------
// fp32 -> bf16 conversion (grid-stride)
// ---------------------------------------------------------------------------
__global__ __launch_bounds__(256) void k_f2b(const float* __restrict__ in,
                                             bf16* __restrict__ out, int n) {
    for (int i = blockIdx.x * 256 + threadIdx.x; i < n; i += gridDim.x * 256)
        out[i] = __float2bfloat16(in[i]);
}

// ---------------------------------------------------------------------------
// All-layer QKV weight pack: Wq/Wk/Wv [L][64][64] fp32 -> wqkv [L][192][64]
// bf16, one preamble launch.  grid (16, L).
// ---------------------------------------------------------------------------
__global__ __launch_bounds__(256) void k_qkvw_all(const float* __restrict__ q,
                                                  const float* __restrict__ k,
                                                  const float* __restrict__ v,
                                                  bf16* __restrict__ out) {
    int l = blockIdx.y;
    int i = blockIdx.x * 256 + threadIdx.x;   // 0..4095
    bf16* o = out + (size_t)l * 12288;
    const size_t off = (size_t)l * 4096 + i;
    o[i]        = __float2bfloat16(q[off]);
    o[i + 4096] = __float2bfloat16(k[off]);
    o[i + 8192] = __float2bfloat16(v[off]);
}

// ---------------------------------------------------------------------------
// QKV projection as one MFMA GEMM: A = h16 as [(b,s,h)][64], W = [192][64]
// q columns (0-63) pre-scaled by 0.125*log2(e).
// ---------------------------------------------------------------------------
__global__ __launch_bounds__(256) void k_qkv_mfma(const bf16* __restrict__ A,
                                                  const bf16* __restrict__ Wqkv,
                                                  bf16* __restrict__ qk,
                                                  bf16* __restrict__ v) {
    __shared__ __align__(16) bf16 As[2][128][32];
    __shared__ __align__(16) bf16 Ws[2][192][32];
    int t = threadIdx.x;
    int w = t >> 6, lane = t & 63;
    int fr = lane & 15, fq = lane >> 4;
    int m0 = blockIdx.x * 128;
    int wm = (w >> 1) * 64;        // row half
    int wc = (w & 1) * 96;         // col half
    int lr = lane >> 2;
    int csw = ((lane & 3) ^ ((lane >> 3) & 3)) * 8;   // swizzled global chunk
    int swz8 = (fq ^ ((fr >> 1) & 3)) * 8;            // swizzled frag-read col

#pragma unroll
    for (int kc = 0; kc < 2; kc++)
#pragma unroll
        for (int i = 0; i < 2; i++) {
            int rb = w * 32 + i * 16;
            __builtin_amdgcn_global_load_lds(
                GPTR(A + (size_t)(m0 + rb + lr) * 64 + kc * 32 + csw),
                LPTR(&As[kc][rb][0]), 16, 0, 0);
        }
#pragma unroll
    for (int kc = 0; kc < 2; kc++)
#pragma unroll
        for (int i = 0; i < 3; i++) {
            int rb = w * 48 + i * 16;
            __builtin_amdgcn_global_load_lds(
                GPTR(Wqkv + (size_t)(rb + lr) * 64 + kc * 32 + csw),
                LPTR(&Ws[kc][rb][0]), 16, 0, 0);
        }
    __syncthreads();

    bf16x8 af[2][4], bw[2][6];
#pragma unroll
    for (int kc = 0; kc < 2; kc++) {
#pragma unroll
        for (int mi = 0; mi < 4; mi++)
            af[kc][mi] = *(const bf16x8*)&As[kc][wm + mi * 16 + fr][swz8];
#pragma unroll
        for (int ni = 0; ni < 6; ni++)
            bw[kc][ni] = *(const bf16x8*)&Ws[kc][wc + ni * 16 + fr][swz8];
    }
    f32x4 acc[4][6] = {};
#pragma unroll
    for (int mi = 0; mi < 4; mi++)
#pragma unroll
        for (int ni = 0; ni < 6; ni++) {
            acc[mi][ni] = __builtin_amdgcn_mfma_f32_16x16x32_bf16(af[0][mi], bw[0][ni], acc[mi][ni], 0, 0, 0);
            acc[mi][ni] = __builtin_amdgcn_mfma_f32_16x16x32_bf16(af[1][mi], bw[1][ni], acc[mi][ni], 0, 0, 0);
        }

#pragma unroll
    for (int mi = 0; mi < 4; mi++)
#pragma unroll
        for (int r = 0; r < 4; r++) {
            size_t mg = m0 + wm + mi * 16 + fq * 4 + r;
#pragma unroll
            for (int ni = 0; ni < 6; ni++) {
                int col = wc + ni * 16 + fr;
                float fv = acc[mi][ni][r];
                if (col < 64) fv *= QSCALE;
                bf16 val = __float2bfloat16(fv);
                if (col < 128) qk[mg * 128 + col] = val;
                else           v[mg * 64 + (col - 128)] = val;
            }
        }
}

// ---------------------------------------------------------------------------
// V transpose + key-permute: v [(b,s,h)][64] -> vt [bh*64 + d][768].
// Within each 32-key block, output pos 8*fq + j holds key 16*(j>>2)+4*fq+(j&3).
// grid (256, 12).
// ---------------------------------------------------------------------------
__global__ __launch_bounds__(256) void k_vt(const bf16* __restrict__ v,
                                            bf16* __restrict__ vt) {
    int bh = blockIdx.x, st = blockIdx.y;
    int b = bh >> 3, h = bh & 7;
    int t = threadIdx.x;
    __shared__ bf16 Ls[64][72];
    int s0 = st * 64;
    for (int j = t; j < 512; j += 256) {
        int si = j >> 3, e8 = (j & 7) * 8;
        int s = s0 + si; if (s > SS - 1) s = SS - 1;
        bf16x8 val = *(const bf16x8*)(v + ((size_t)(b * SS + s) * 8 + h) * 64 + e8);
        *(bf16x8*)&Ls[si][e8] = val;
    }
    __syncthreads();
    for (int j = t; j < 512; j += 256) {
        int d = j >> 3, o8 = (j & 7) * 8;       // output chunk base (0..56)
        int half = o8 & 32, fqv = (o8 & 31) >> 3;
        __align__(16) bf16 tmp[8];
#pragma unroll
        for (int i = 0; i < 8; i++)
            tmp[i] = Ls[half + 4 * fqv + 16 * (i >> 2) + (i & 3)][d];
        *(bf16x8*)(vt + ((size_t)bh * 64 + d) * VTS + s0 + o8) = *(bf16x8*)tmp;
    }
}

// ---------------------------------------------------------------------------
// Flash MFMA attention (harness-proven round-5 kernel, unchanged).
// grid (256 bh, 3 q-tiles of 256). Per block: 4 waves x 64 q-rows.
// ---------------------------------------------------------------------------
__global__ __launch_bounds__(256) void k_attn_mfma(const bf16* __restrict__ qk,
                                                   const bf16* __restrict__ vt,
                                                   bf16* __restrict__ ao) {
    int bh = blockIdx.x, qt = blockIdx.y;
    int b = bh >> 3, h = bh & 7;
    int t = threadIdx.x;
    int w = t >> 6, lane = t & 63;
    int fr = lane & 15, fq = lane >> 4;
    int lr = lane >> 2;
    int csw = ((lane & 3) ^ ((lane >> 3) & 3)) * 8;   // swizzled global chunk
    int swz8 = (fq ^ ((fr >> 1) & 3)) * 8;            // swizzled frag-read col
    int q0 = qt * 256;

    __shared__ __align__(16) bf16 Ks[2][2][64][32];   // [buf][slice][key][e]
    __shared__ __align__(16) bf16 Vs[2][2][64][32];   // [buf][slice][d][keypos]

    // Q fragments direct from global (once per block): B-frag Q[qrow][e]
    bf16x8 qf[4][2];
#pragma unroll
    for (int qs = 0; qs < 4; qs++) {
        int row = q0 + w * 64 + qs * 16 + fr;
        if (row > SS - 1) row = SS - 1;
        size_t gb = ((size_t)(b * SS + row) * 8 + h) * 128;
        qf[qs][0] = *(const bf16x8*)(qk + gb + fq * 8);
        qf[qs][1] = *(const bf16x8*)(qk + gb + 32 + fq * 8);
    }

    f32x4 o_acc[4][4] = {};                 // [qset][d-tile]
    float l_[4] = {0.f, 0.f, 0.f, 0.f};     // per-lane partial denominators

    auto STAGE = [&](int buf, int kt) {
        int k0 = kt * 64;
        int krow = k0 + w * 16 + lr; if (krow > SS - 1) krow = SS - 1;
        size_t kgb = ((size_t)(b * SS + krow) * 8 + h) * 128 + 64;
        size_t vgb = ((size_t)bh * 64 + w * 16 + lr) * VTS + k0;
#pragma unroll
        for (int p = 0; p < 2; p++) {
            __builtin_amdgcn_global_load_lds(GPTR(qk + kgb + p * 32 + csw),
                                             LPTR(&Ks[buf][p][w * 16][0]), 16, 0, 0);
            __builtin_amdgcn_global_load_lds(GPTR(vt + vgb + p * 32 + csw),
                                             LPTR(&Vs[buf][p][w * 16][0]), 16, 0, 0);
        }
    };

    STAGE(0, 0);
    for (int kt = 0; kt < 12; kt++) {
        int cur = kt & 1;
        __syncthreads();
        if (kt < 11) STAGE(cur ^ 1, kt + 1);   // fire-and-forget prefetch

        // K fragments: A[m=key][k=e], shared across all q-sets
        bf16x8 kf[4][2];
#pragma unroll
        for (int n = 0; n < 4; n++) {
            kf[n][0] = *(const bf16x8*)&Ks[cur][0][n * 16 + fr][swz8];
            kf[n][1] = *(const bf16x8*)&Ks[cur][1][n * 16 + fr][swz8];
        }

        bf16x8 pf[4][2];                      // [qset][key-slice]
#pragma unroll
        for (int qs = 0; qs < 4; qs++) {
            // S^T tiles (log2-domain scores; Q pre-scaled)
            f32x4 st[4] = {};
            __builtin_amdgcn_s_setprio(1);
#pragma unroll
            for (int n = 0; n < 4; n++) {
                st[n] = __builtin_amdgcn_mfma_f32_16x16x32_bf16(kf[n][0], qf[qs][0], st[n], 0, 0, 0);
                st[n] = __builtin_amdgcn_mfma_f32_16x16x32_bf16(kf[n][1], qf[qs][1], st[n], 0, 0, 0);
            }
            __builtin_amdgcn_s_setprio(0);
            if (kt == 11) {   // mask invalid keys (uniform branch, last tile only)
#pragma unroll
                for (int n = 0; n < 4; n++) {
                    int kb = 704 + n * 16 + fq * 4;
#pragma unroll
                    for (int r = 0; r < 4; r++)
                        if (kb + r >= SS) st[n][r] = -1e30f;
                }
            }
            // fixed-max softmax numerator: P = exp2(st); accumulate local l
            float ls = 0.f;
#pragma unroll
            for (int n = 0; n < 4; n++)
#pragma unroll
                for (int r = 0; r < 4; r++) {
                    float p = __builtin_amdgcn_exp2f(st[n][r]);
                    st[n][r] = p;
                    ls += p;
                }
            l_[qs] += ls;
            // in-lane repack to PV B-frags (key-permuted vt makes this exact)
            bf16x8 t0, t1;
#pragma unroll
            for (int e = 0; e < 4; e++) {
                t0[e]     = (__bf16)st[0][e];
                t0[e + 4] = (__bf16)st[1][e];
                t1[e]     = (__bf16)st[2][e];
                t1[e + 4] = (__bf16)st[3][e];
            }
            pf[qs][0] = t0;
            pf[qs][1] = t1;
        }

        // PV: O^T += V^T · P  (A = V-frag swizzled+key-permuted, B = in-reg P)
        __builtin_amdgcn_s_setprio(1);
#pragma unroll
        for (int dt = 0; dt < 4; dt++) {
            bf16x8 vf0 = *(const bf16x8*)&Vs[cur][0][dt * 16 + fr][swz8];
            bf16x8 vf1 = *(const bf16x8*)&Vs[cur][1][dt * 16 + fr][swz8];
#pragma unroll
            for (int qs = 0; qs < 4; qs++) {
                o_acc[qs][dt] = __builtin_amdgcn_mfma_f32_16x16x32_bf16(vf0, pf[qs][0], o_acc[qs][dt], 0, 0, 0);
                o_acc[qs][dt] = __builtin_amdgcn_mfma_f32_16x16x32_bf16(vf1, pf[qs][1], o_acc[qs][dt], 0, 0, 0);
            }
        }
        __builtin_amdgcn_s_setprio(0);
    }

    // epilogue: O^T C-layout row=d=dt*16+fq*4+r, col=qrow -> ao[s][h*64+d]
#pragma unroll
    for (int qs = 0; qs < 4; qs++) {
        int srow = q0 + w * 64 + qs * 16 + fr;
        if (srow < SS) {
            float lt = l_[qs];
            lt += __shfl_xor(lt, 16);
            lt += __shfl_xor(lt, 32);
            float inv = 1.f / lt;
            bf16* dst = ao + ((size_t)(b * SS + srow) * 8 + h) * 64;
#pragma unroll
            for (int dt = 0; dt < 4; dt++) {
                __align__(8) bf16 tb[4];
#pragma unroll
                for (int r = 0; r < 4; r++)
                    tb[r] = __float2bfloat16(o_acc[qs][dt][r] * inv);
                *(unsigned long long*)(dst + dt * 16 + fq * 4) =
                    *(unsigned long long*)tb;
            }
        }
    }
}

// ---------------------------------------------------------------------------
// bf16 MFMA GEMM: C = act(A[M,K] @ W[N,K]^T + b)   (round-2 proven, exact:
// BK=32, 2-phase double-buffer, 32 KB LDS — the verified local optimum).
//  - grid (N/128, M/128) n-fastest; XCD-chunked swizzle (nwg % 8 == 0).
// ---------------------------------------------------------------------------
template <bool RELU, bool OUT_BF16>
__global__ __launch_bounds__(256) void k_gemm_mfma(const bf16* __restrict__ A,
                                                   const bf16* __restrict__ W,
                                                   const float* __restrict__ bias,
                                                   void* __restrict__ Cout,
                                                   int M, int N, int K) {
    __shared__ __align__(16) bf16 As[2][128 * 32];
    __shared__ __align__(16) bf16 Ws[2][128 * 32];
    int t = threadIdx.x;
    int wave = t >> 6, lane = t & 63;
    // XCD-chunked bijective remap (requires gridDim.x*gridDim.y % 8 == 0)
    int nbx = gridDim.x;
    int nwg = nbx * gridDim.y;
    int bid = blockIdx.y * nbx + blockIdx.x;
    int cpx = nwg >> 3;
    int swz = (bid & 7) * cpx + (bid >> 3);
    int n0 = (swz % nbx) * 128;
    int m0 = (swz / nbx) * 128;
    int wm = (wave >> 1) * 64, wn = (wave & 1) * 64;
    int fr = lane & 15, fq = lane >> 4;
    int csw = ((lane & 3) ^ ((lane >> 3) & 3)) * 8;   // swizzled global chunk
    int swz8 = (fq ^ ((fr >> 1) & 3)) * 8;            // swizzled frag-read col

    f32x4 acc[4][4] = {};

    int r0 = wave * 16 + (lane >> 2);
    int r1 = r0 + 64;

    auto STAGE = [&](int buf, int k0) {
        __builtin_amdgcn_global_load_lds(GPTR(A + (size_t)(m0 + r0) * K + k0 + csw),
                                         LPTR((char*)&As[buf][0] + (wave << 10)), 16, 0, 0);
        __builtin_amdgcn_global_load_lds(GPTR(A + (size_t)(m0 + r1) * K + k0 + csw),
                                         LPTR((char*)&As[buf][0] + (wave << 10) + 4096), 16, 0, 0);
        __builtin_amdgcn_global_load_lds(GPTR(W + (size_t)(n0 + r0) * K + k0 + csw),
                                         LPTR((char*)&Ws[buf][0] + (wave << 10)), 16, 0, 0);
        __builtin_amdgcn_global_load_lds(GPTR(W + (size_t)(n0 + r1) * K + k0 + csw),
                                         LPTR((char*)&Ws[buf][0] + (wave << 10) + 4096), 16, 0, 0);
    };

    int nk = K >> 5;
    STAGE(0, 0);
    for (int kt = 0; kt < nk; kt++) {
        int cur = kt & 1;
        __syncthreads();
        if (kt + 1 < nk) STAGE(cur ^ 1, (kt + 1) << 5);

        bf16x8 af[4], bfr[4];
#pragma unroll
        for (int i = 0; i < 4; i++)
            af[i] = *(const bf16x8*)(&As[cur][0] + (wm + i * 16 + fr) * 32 + swz8);
#pragma unroll
        for (int i = 0; i < 4; i++)
            bfr[i] = *(const bf16x8*)(&Ws[cur][0] + (wn + i * 16 + fr) * 32 + swz8);
#pragma unroll
        for (int mi = 0; mi < 4; mi++)
#pragma unroll
            for (int ni = 0; ni < 4; ni++)
                acc[mi][ni] = __builtin_amdgcn_mfma_f32_16x16x32_bf16(
                    af[mi], bfr[ni], acc[mi][ni], 0, 0, 0);
    }

    float bv[4];
#pragma unroll
    for (int ni = 0; ni < 4; ni++) bv[ni] = bias[n0 + wn + ni * 16 + fr];
#pragma unroll
    for (int mi = 0; mi < 4; mi++) {
#pragma unroll
        for (int r = 0; r < 4; r++) {
            int mg = m0 + wm + mi * 16 + fq * 4 + r;
#pragma unroll
            for (int ni = 0; ni < 4; ni++) {
                float val = acc[mi][ni][r] + bv[ni];
                if (RELU) val = fmaxf(val, 0.f);
                int ng = n0 + wn + ni * 16 + fr;
                if (OUT_BF16)
                    ((bf16*)Cout)[(size_t)mg * N + ng] = __float2bfloat16(val);
                else
                    ((float*)Cout)[(size_t)mg * N + ng] = val;
            }
        }
    }
}

// ---------------------------------------------------------------------------
// Fused residual add + LayerNorm.
// AF16: `a` is bf16 (else fp32).  BRES16: residual `bres` is bf16.
// WF32: also write fp32 out.  Residual math is fp32 throughout.
// ---------------------------------------------------------------------------
template <bool AF16, bool BRES16, bool WF32>
__global__ __launch_bounds__(128) void k_add_ln(const void* __restrict__ a,
                                                const void* __restrict__ bres,
                                                const float* __restrict__ w,
                                                const float* __restrict__ bias,
                                                float* out,
                                                bf16* __restrict__ out16) {
    int row = blockIdx.x;
    int t = threadIdx.x;
    float4 xa;
    if (AF16) {
        ushort4 ua = ((const ushort4*)((const bf16*)a + (size_t)row * DD))[t];
        xa.x = __bfloat162float(*(bf16*)&ua.x);
        xa.y = __bfloat162float(*(bf16*)&ua.y);
        xa.z = __bfloat162float(*(bf16*)&ua.z);
        xa.w = __bfloat162float(*(bf16*)&ua.w);
    } else {
        xa = ((const float4*)((const float*)a + (size_t)row * DD))[t];
    }
    float4 xb;
    if (BRES16) {
        ushort4 ub = ((const ushort4*)((const bf16*)bres + (size_t)row * DD))[t];
        xb.x = __bfloat162float(*(bf16*)&ub.x);
        xb.y = __bfloat162float(*(bf16*)&ub.y);
        xb.z = __bfloat162float(*(bf16*)&ub.z);
        xb.w = __bfloat162float(*(bf16*)&ub.w);
    } else {
        xb = ((const float4*)((const float*)bres + (size_t)row * DD))[t];
    }
    float4 vv;
    vv.x = xa.x + xb.x; vv.y = xa.y + xb.y;
    vv.z = xa.z + xb.z; vv.w = xa.w + xb.w;
    float s  = vv.x + vv.y + vv.z + vv.w;
    float sq = vv.x * vv.x + vv.y * vv.y + vv.z * vv.z + vv.w * vv.w;
#pragma unroll
    for (int off = 32; off > 0; off >>= 1) {
        s  += __shfl_down(s, off);
        sq += __shfl_down(sq, off);
    }
    __shared__ float red[4];
    if ((t & 63) == 0) { red[(t >> 6) * 2] = s; red[(t >> 6) * 2 + 1] = sq; }
    __syncthreads();
    float S1 = red[0] + red[2], S2 = red[1] + red[3];
    float mean = S1 * (1.f / DD);
    float var  = S2 * (1.f / DD) - mean * mean;
    float inv  = rsqrtf(var + 1e-5f);
    float4 wv = ((const float4*)w)[t];
    float4 bv = ((const float4*)bias)[t];
    float4 o;
    o.x = (vv.x - mean) * inv * wv.x + bv.x;
    o.y = (vv.y - mean) * inv * wv.y + bv.y;
    o.z = (vv.z - mean) * inv * wv.z + bv.z;
    o.w = (vv.w - mean) * inv * wv.w + bv.w;
    if (WF32)
        ((float4*)(out + (size_t)row * DD))[t] = o;
    bf16 h0 = __float2bfloat16(o.x), h1 = __float2bfloat16(o.y);
    bf16 h2 = __float2bfloat16(o.z), h3 = __float2bfloat16(o.w);
    ushort4 u;
    u.x = *(unsigned short*)&h0; u.y = *(unsigned short*)&h1;
    u.z = *(unsigned short*)&h2; u.w = *(unsigned short*)&h3;
    ((ushort4*)(out16 + (size_t)row * DD))[t] = u;
}

// ---------------------------------------------------------------------------
extern "C" void kernel_launch(void* const* d_in, const int* in_sizes, int n_in,
                              void* d_out, int out_size, void* d_ws, size_t ws_size,
                              hipStream_t stream) {
    const int*   x    = (const int*)d_in[0];
    const float* emb  = (const float*)d_in[1];
    const float* pe   = (const float*)d_in[2];
    const float* Wq   = (const float*)d_in[3];
    const float* Wk   = (const float*)d_in[4];
    const float* Wv   = (const float*)d_in[5];
    const float* Wo   = (const float*)d_in[6];
    const float* bo   = (const float*)d_in[7];
    const float* ln1w = (const float*)d_in[8];
    const float* ln1b = (const float*)d_in[9];
    const float* W1   = (const float*)d_in[10];
    const float* b1   = (const float*)d_in[11];
    const float* W2   = (const float*)d_in[12];
    const float* b2   = (const float*)d_in[13];
    const float* ln2w = (const float*)d_in[14];
    const float* ln2b = (const float*)d_in[15];

    float* h  = (float*)d_out;     // fp32 output, written only by last ln2
    float* ws = (float*)d_ws;
    // Region A [0, NBUF): qk bf16 [MROWS][128] -> wo16 bf16 -> ff16 bf16
    bf16*  qkbuf  = (bf16*)ws;
    bf16*  wo16   = (bf16*)ws;
    bf16*  ff16   = (bf16*)ws;
    // Region B+C [NBUF, 3*NBUF): v/vt (dead after attn) -> f1b bf16 [23808][2048]
    bf16*  v_buf  = (bf16*)(ws + NBUF);
    bf16*  vt_buf = (bf16*)(ws + NBUF + NBUF / 2);
    bf16*  f1b    = (bf16*)(ws + NBUF);
    // Region D [3*NBUF, 3.5*NBUF): aob -> n1b (bf16 [NROWS][512])
    bf16*  regD   = (bf16*)(ws + 3 * NBUF);
    // Region E [3.5*NBUF, 4*NBUF): h16 (bf16 residual carrier)
    bf16*  h16    = regD + NBUF;
    // Weights (bf16)
    bf16*  wob16  = h16 + NBUF;
    bf16*  w1b16  = wob16 + (size_t)LL * DD * DD;
    bf16*  w2b16  = w1b16 + (size_t)LL * EXPAND * DD * DD;
    bf16*  wqkvA  = w2b16 + (size_t)LL * DD * EXPAND * DD;   // [L][192][64]

    k_f2b<<<2048, 256, 0, stream>>>(Wo, wob16, LL * DD * DD);
    k_f2b<<<4096, 256, 0, stream>>>(W1, w1b16, LL * EXPAND * DD * DD);
    k_f2b<<<4096, 256, 0, stream>>>(W2, w2b16, LL * EXPAND * DD * DD);
    k_qkvw_all<<<dim3(16, LL), 256, 0, stream>>>(Wq, Wk, Wv, wqkvA);
    k_embed<<<NROWS, 128, 0, stream>>>(x, emb, pe, h16);

    for (int l = 0; l < LL; l++) {
        k_qkv_mfma<<<MROWS / 128, 256, 0, stream>>>(h16, wqkvA + (size_t)l * 12288,
                                                    qkbuf, v_buf);
        k_vt<<<dim3(256, 12), 256, 0, stream>>>(v_buf, vt_buf);
        k_attn_mfma<<<dim3(256, 3), 256, 0, stream>>>(qkbuf, vt_buf, regD);
        // Wo output kept bf16 (pre-LN tensor; LN renormalizes the rounding)
        k_gemm_mfma<false, true><<<dim3(DD / 128, NROWS / 128), 256, 0, stream>>>(
            regD, wob16 + (size_t)l * DD * DD, bo + (size_t)l * DD, wo16,
            NROWS, DD, DD);
        // residual read from the bf16 carrier h16 (same values the QKV path
        // consumed); n1 kept only as bf16 (regD)
        k_add_ln<true, true, false><<<NROWS, 128, 0, stream>>>(wo16, h16,
            ln1w + (size_t)l * DD, ln1b + (size_t)l * DD, nullptr, regD);
        k_gemm_mfma<true, true><<<dim3((EXPAND * DD) / 128, NROWS / 128), 256, 0, stream>>>(
            regD, w1b16 + (size_t)l * EXPAND * DD * DD, b1 + (size_t)l * EXPAND * DD,
            f1b, NROWS, EXPAND * DD, DD);
        // FF2 output kept bf16 (pre-LN tensor)
        k_gemm_mfma<false, true><<<dim3(DD / 128, NROWS / 128), 256, 0, stream>>>(
            f1b, w2b16 + (size_t)l * DD * EXPAND * DD, b2 + (size_t)l * DD,
            ff16, NROWS, DD, EXPAND * DD);
        // layers 0-2: bf16 carrier only; last layer also writes fp32 d_out
        if (l + 1 < LL)
            k_add_ln<true, true, false><<<NROWS, 128, 0, stream>>>(ff16, regD,
                ln2w + (size_t)l * DD, ln2b + (size_t)l * DD, nullptr, h16);
        else
            k_add_ln<true, true, true><<<NROWS, 128, 0, stream>>>(ff16, regD,
                ln2w + (size_t)l * DD, ln2b + (size_t)l * DD, h, h16);
    }
}